// Round 1
// baseline (158.358 us; speedup 1.0000x reference)
//
#include <hip/hip_runtime.h>

#define HW    128
#define CDIM  128
#define BDIM  32
#define NPIX  (HW * HW)      // 16384
#define N1    (HW - 1)       // 127
#define SLABS 64             // slabs per batch in k1; 256 pixels per slab

// ---------------------------------------------------------------------------
// Kernel 1: per-block partial selector logits.
// grid = 32 b * 64 slabs, block = 256 threads.
// Thread (c4 = tid&31, po = tid>>5) accumulates float4 over 32 pixels,
// multiplies by W_sel rows, block-reduces to 4 floats per block.
// ---------------------------------------------------------------------------
__global__ __launch_bounds__(256) void k1_partial(
    const float* __restrict__ x,
    const float* __restrict__ Wsel,
    float* __restrict__ partial) {
    int blk  = blockIdx.x;        // 0..2047
    int b    = blk >> 6;          // 0..31
    int slab = blk & 63;          // 0..63
    int tid  = threadIdx.x;       // 0..255
    int c4   = tid & 31;          // float4 index within a C-row
    int po   = tid >> 5;          // 0..7 pixel offset

    const float4* xb = (const float4*)(x + (size_t)b * NPIX * CDIM);
    float4 acc = make_float4(0.f, 0.f, 0.f, 0.f);
    int pixbase = slab * 256 + po;
    #pragma unroll 4
    for (int k = 0; k < 32; ++k) {
        int pix = pixbase + k * 8;
        float4 v = xb[(size_t)pix * 32 + c4];
        acc.x += v.x; acc.y += v.y; acc.z += v.z; acc.w += v.w;
    }

    // logit contribution: lg[i] = sum_j acc[j] * W_sel[c4*4+j][i]
    const float4* W4 = (const float4*)Wsel;   // W4[c] = W_sel[c][0..3]
    float4 w0 = W4[c4 * 4 + 0];
    float4 w1 = W4[c4 * 4 + 1];
    float4 w2 = W4[c4 * 4 + 2];
    float4 w3 = W4[c4 * 4 + 3];
    float4 lg;
    lg.x = acc.x * w0.x + acc.y * w1.x + acc.z * w2.x + acc.w * w3.x;
    lg.y = acc.x * w0.y + acc.y * w1.y + acc.z * w2.y + acc.w * w3.y;
    lg.z = acc.x * w0.z + acc.y * w1.z + acc.z * w2.z + acc.w * w3.z;
    lg.w = acc.x * w0.w + acc.y * w1.w + acc.z * w2.w + acc.w * w3.w;

    __shared__ float4 s[256];
    s[tid] = lg;
    __syncthreads();
    #pragma unroll
    for (int off = 128; off > 0; off >>= 1) {
        if (tid < off) {
            float4 a = s[tid], c = s[tid + off];
            a.x += c.x; a.y += c.y; a.z += c.z; a.w += c.w;
            s[tid] = a;
        }
        __syncthreads();
    }
    if (tid == 0) ((float4*)partial)[blk] = s[0];
}

// ---------------------------------------------------------------------------
// Kernel 2: reduce 64 partials per batch, add bias, softmax -> weights[b][4].
// grid = 32 blocks, block = 64 threads (one wave).
// ---------------------------------------------------------------------------
__global__ __launch_bounds__(64) void k2_weights(
    const float* __restrict__ partial,
    const float* __restrict__ bsel,
    float* __restrict__ wts) {
    int b = blockIdx.x;
    int t = threadIdx.x;  // 0..63
    float4 v = ((const float4*)partial)[b * 64 + t];
    #pragma unroll
    for (int off = 32; off > 0; off >>= 1) {
        v.x += __shfl_down(v.x, off, 64);
        v.y += __shfl_down(v.y, off, 64);
        v.z += __shfl_down(v.z, off, 64);
        v.w += __shfl_down(v.w, off, 64);
    }
    if (t == 0) {
        const float inv = 1.0f / (float)NPIX;
        float l0 = v.x * inv + bsel[0];
        float l1 = v.y * inv + bsel[1];
        float l2 = v.z * inv + bsel[2];
        float l3 = v.w * inv + bsel[3];
        float m  = fmaxf(fmaxf(l0, l1), fmaxf(l2, l3));
        float e0 = expf(l0 - m), e1 = expf(l1 - m);
        float e2 = expf(l2 - m), e3 = expf(l3 - m);
        float inv_s = 1.0f / (e0 + e1 + e2 + e3);
        wts[b * 4 + 0] = e0 * inv_s;
        wts[b * 4 + 1] = e1 * inv_s;
        wts[b * 4 + 2] = e2 * inv_s;
        wts[b * 4 + 3] = e3 * inv_s;
    }
}

// ---------------------------------------------------------------------------
// Kernel 3: weighted rotation sum via 4-orbits.
// Orbit rep (h,w) in [0,64)^2; the 4 rotated positions permute cyclically, so
// one thread reads 4 float4s and writes 4 float4s: x read once, out written
// once. grid = 32 b * 512 groups, block = 256 (8 orbits * 32 c-float4s).
// ---------------------------------------------------------------------------
__device__ __forceinline__ float4 comb(float s0, float s1, float s2, float s3,
                                       float4 a, float4 b, float4 c, float4 d) {
    float4 r;
    r.x = s0 * a.x + s1 * b.x + s2 * c.x + s3 * d.x;
    r.y = s0 * a.y + s1 * b.y + s2 * c.y + s3 * d.y;
    r.z = s0 * a.z + s1 * b.z + s2 * c.z + s3 * d.z;
    r.w = s0 * a.w + s1 * b.w + s2 * c.w + s3 * d.w;
    return r;
}

__global__ __launch_bounds__(256) void k3_rot(
    const float* __restrict__ x,
    const float* __restrict__ wts,
    float* __restrict__ out) {
    int blk = blockIdx.x;           // 0..16383
    int b   = blk >> 9;             // 0..31
    int grp = blk & 511;            // 0..511
    int tid = threadIdx.x;
    int c4  = tid & 31;             // float4 index within C-row
    int o   = tid >> 5;             // 0..7
    int orbit = grp * 8 + o;        // 0..4095
    int h = orbit >> 6;             // 0..63
    int w = orbit & 63;             // 0..63

    float s0 = wts[b * 4 + 0];
    float s1 = wts[b * 4 + 1];
    float s2 = wts[b * 4 + 2];
    float s3 = wts[b * 4 + 3];

    const float4* xb = (const float4*)(x + (size_t)b * NPIX * CDIM);
    float4*       ob = (float4*)(out + (size_t)b * NPIX * CDIM);

    int p0 = (h * HW + w) * 32 + c4;
    int p1 = (w * HW + (N1 - h)) * 32 + c4;
    int p2 = ((N1 - h) * HW + (N1 - w)) * 32 + c4;
    int p3 = ((N1 - w) * HW + h) * 32 + c4;

    float4 a0 = xb[p0];
    float4 a1 = xb[p1];
    float4 a2 = xb[p2];
    float4 a3 = xb[p3];

    // out[p_k] = s0*x[p_k] + s1*x[p_{k+1}] + s2*x[p_{k+2}] + s3*x[p_{k+3}]
    ob[p0] = comb(s0, s1, s2, s3, a0, a1, a2, a3);
    ob[p1] = comb(s0, s1, s2, s3, a1, a2, a3, a0);
    ob[p2] = comb(s0, s1, s2, s3, a2, a3, a0, a1);
    ob[p3] = comb(s0, s1, s2, s3, a3, a0, a1, a2);
}

extern "C" void kernel_launch(void* const* d_in, const int* in_sizes, int n_in,
                              void* d_out, int out_size, void* d_ws, size_t ws_size,
                              hipStream_t stream) {
    const float* x    = (const float*)d_in[0];
    const float* Wsel = (const float*)d_in[1];
    const float* bsel = (const float*)d_in[2];
    float* out = (float*)d_out;

    float* partial = (float*)d_ws;                                 // 2048*4 floats
    float* wts     = (float*)((char*)d_ws + 2048 * 4 * sizeof(float)); // 32*4 floats

    k1_partial<<<BDIM * SLABS, 256, 0, stream>>>(x, Wsel, partial);
    k2_weights<<<BDIM, 64, 0, stream>>>(partial, bsel, wts);
    k3_rot<<<BDIM * 512, 256, 0, stream>>>(x, wts, out);
}

// Round 2
// 123.944 us; speedup vs baseline: 1.2777x; 1.2777x over previous
//
#include <hip/hip_runtime.h>

#define HW    128
#define CDIM  128
#define BDIM  32
#define NPIX  (HW * HW)      // 16384
#define N1    (HW - 1)       // 127
#define SLABS 64             // slabs per batch in k1; 256 pixels per slab

typedef float vfloat4 __attribute__((ext_vector_type(4)));

__device__ __forceinline__ void nt_store4(float4* p, float4 v) {
    vfloat4 t;
    t.x = v.x; t.y = v.y; t.z = v.z; t.w = v.w;
    __builtin_nontemporal_store(t, (vfloat4*)p);
}

// ---------------------------------------------------------------------------
// Kernel 1: per-block partial selector logits.
// grid = 32 b * 64 slabs, block = 256 threads.
// Normal (caching) loads: this pass deliberately warms the 256 MiB L3 with x.
// ---------------------------------------------------------------------------
__global__ __launch_bounds__(256) void k1_partial(
    const float* __restrict__ x,
    const float* __restrict__ Wsel,
    float* __restrict__ partial) {
    int blk  = blockIdx.x;        // 0..2047
    int b    = blk >> 6;          // 0..31
    int slab = blk & 63;          // 0..63
    int tid  = threadIdx.x;       // 0..255
    int c4   = tid & 31;          // float4 index within a C-row
    int po   = tid >> 5;          // 0..7 pixel offset

    const float4* xb = (const float4*)(x + (size_t)b * NPIX * CDIM);
    float4 acc = make_float4(0.f, 0.f, 0.f, 0.f);
    int pixbase = slab * 256 + po;
    #pragma unroll 4
    for (int k = 0; k < 32; ++k) {
        int pix = pixbase + k * 8;
        float4 v = xb[(size_t)pix * 32 + c4];
        acc.x += v.x; acc.y += v.y; acc.z += v.z; acc.w += v.w;
    }

    // logit contribution: lg[i] = sum_j acc[j] * W_sel[c4*4+j][i]
    const float4* W4 = (const float4*)Wsel;   // W4[c] = W_sel[c][0..3]
    float4 w0 = W4[c4 * 4 + 0];
    float4 w1 = W4[c4 * 4 + 1];
    float4 w2 = W4[c4 * 4 + 2];
    float4 w3 = W4[c4 * 4 + 3];
    float4 lg;
    lg.x = acc.x * w0.x + acc.y * w1.x + acc.z * w2.x + acc.w * w3.x;
    lg.y = acc.x * w0.y + acc.y * w1.y + acc.z * w2.y + acc.w * w3.y;
    lg.z = acc.x * w0.z + acc.y * w1.z + acc.z * w2.z + acc.w * w3.z;
    lg.w = acc.x * w0.w + acc.y * w1.w + acc.z * w2.w + acc.w * w3.w;

    __shared__ float4 s[256];
    s[tid] = lg;
    __syncthreads();
    #pragma unroll
    for (int off = 128; off > 0; off >>= 1) {
        if (tid < off) {
            float4 a = s[tid], c = s[tid + off];
            a.x += c.x; a.y += c.y; a.z += c.z; a.w += c.w;
            s[tid] = a;
        }
        __syncthreads();
    }
    if (tid == 0) ((float4*)partial)[blk] = s[0];
}

// ---------------------------------------------------------------------------
// Kernel 2: reduce 64 partials per batch, add bias, softmax -> weights[b][4].
// ---------------------------------------------------------------------------
__global__ __launch_bounds__(64) void k2_weights(
    const float* __restrict__ partial,
    const float* __restrict__ bsel,
    float* __restrict__ wts) {
    int b = blockIdx.x;
    int t = threadIdx.x;  // 0..63
    float4 v = ((const float4*)partial)[b * 64 + t];
    #pragma unroll
    for (int off = 32; off > 0; off >>= 1) {
        v.x += __shfl_down(v.x, off, 64);
        v.y += __shfl_down(v.y, off, 64);
        v.z += __shfl_down(v.z, off, 64);
        v.w += __shfl_down(v.w, off, 64);
    }
    if (t == 0) {
        const float inv = 1.0f / (float)NPIX;
        float l0 = v.x * inv + bsel[0];
        float l1 = v.y * inv + bsel[1];
        float l2 = v.z * inv + bsel[2];
        float l3 = v.w * inv + bsel[3];
        float m  = fmaxf(fmaxf(l0, l1), fmaxf(l2, l3));
        float e0 = expf(l0 - m), e1 = expf(l1 - m);
        float e2 = expf(l2 - m), e3 = expf(l3 - m);
        float inv_s = 1.0f / (e0 + e1 + e2 + e3);
        wts[b * 4 + 0] = e0 * inv_s;
        wts[b * 4 + 1] = e1 * inv_s;
        wts[b * 4 + 2] = e2 * inv_s;
        wts[b * 4 + 3] = e3 * inv_s;
    }
}

// ---------------------------------------------------------------------------
// Kernel 3: weighted rotation sum via 4-orbits.
// x reads: normal (should hit the L3 warmed by k1).
// out writes: NONTEMPORAL (no-allocate) so the store stream does not evict x
// from the Infinity Cache before we finish re-reading it.
// ---------------------------------------------------------------------------
__device__ __forceinline__ float4 comb(float s0, float s1, float s2, float s3,
                                       float4 a, float4 b, float4 c, float4 d) {
    float4 r;
    r.x = s0 * a.x + s1 * b.x + s2 * c.x + s3 * d.x;
    r.y = s0 * a.y + s1 * b.y + s2 * c.y + s3 * d.y;
    r.z = s0 * a.z + s1 * b.z + s2 * c.z + s3 * d.z;
    r.w = s0 * a.w + s1 * b.w + s2 * c.w + s3 * d.w;
    return r;
}

__global__ __launch_bounds__(256) void k3_rot(
    const float* __restrict__ x,
    const float* __restrict__ wts,
    float* __restrict__ out) {
    int blk = blockIdx.x;           // 0..16383
    int b   = blk >> 9;             // 0..31
    int grp = blk & 511;            // 0..511
    int tid = threadIdx.x;
    int c4  = tid & 31;             // float4 index within C-row
    int o   = tid >> 5;             // 0..7
    int orbit = grp * 8 + o;        // 0..4095
    int h = orbit >> 6;             // 0..63
    int w = orbit & 63;             // 0..63

    float s0 = wts[b * 4 + 0];
    float s1 = wts[b * 4 + 1];
    float s2 = wts[b * 4 + 2];
    float s3 = wts[b * 4 + 3];

    const float4* xb = (const float4*)(x + (size_t)b * NPIX * CDIM);
    float4*       ob = (float4*)(out + (size_t)b * NPIX * CDIM);

    int p0 = (h * HW + w) * 32 + c4;
    int p1 = (w * HW + (N1 - h)) * 32 + c4;
    int p2 = ((N1 - h) * HW + (N1 - w)) * 32 + c4;
    int p3 = ((N1 - w) * HW + h) * 32 + c4;

    float4 a0 = xb[p0];
    float4 a1 = xb[p1];
    float4 a2 = xb[p2];
    float4 a3 = xb[p3];

    // out[p_k] = s0*x[p_k] + s1*x[p_{k+1}] + s2*x[p_{k+2}] + s3*x[p_{k+3}]
    nt_store4(&ob[p0], comb(s0, s1, s2, s3, a0, a1, a2, a3));
    nt_store4(&ob[p1], comb(s0, s1, s2, s3, a1, a2, a3, a0));
    nt_store4(&ob[p2], comb(s0, s1, s2, s3, a2, a3, a0, a1));
    nt_store4(&ob[p3], comb(s0, s1, s2, s3, a3, a0, a1, a2));
}

extern "C" void kernel_launch(void* const* d_in, const int* in_sizes, int n_in,
                              void* d_out, int out_size, void* d_ws, size_t ws_size,
                              hipStream_t stream) {
    const float* x    = (const float*)d_in[0];
    const float* Wsel = (const float*)d_in[1];
    const float* bsel = (const float*)d_in[2];
    float* out = (float*)d_out;

    float* partial = (float*)d_ws;                                 // 2048*4 floats
    float* wts     = (float*)((char*)d_ws + 2048 * 4 * sizeof(float)); // 32*4 floats

    k1_partial<<<BDIM * SLABS, 256, 0, stream>>>(x, Wsel, partial);
    k2_weights<<<BDIM, 64, 0, stream>>>(partial, bsel, wts);
    k3_rot<<<BDIM * 512, 256, 0, stream>>>(x, wts, out);
}